// Round 5
// baseline (171.897 us; speedup 1.0000x reference)
//
#include <hip/hip_runtime.h>
#include <hip/hip_bf16.h>
#include <math.h>

typedef __attribute__((ext_vector_type(8))) short bf16x8;
typedef __attribute__((ext_vector_type(4))) float f32x4;

#define MFMA16 __builtin_amdgcn_mfma_f32_16x16x32_bf16

static constexpr int TSEQ = 4096;
static constexpr int EMB = 1024;
static constexpr int HD = 64;

__device__ __forceinline__ unsigned short f2bf(float f) {
    unsigned u = __builtin_bit_cast(unsigned, f);
    u += 0x7fffu + ((u >> 16) & 1u);
    return (unsigned short)(u >> 16);
}
__device__ __forceinline__ int pk2bf(float a, float b) {
    return (int)((unsigned)f2bf(a) | ((unsigned)f2bf(b) << 16));
}

union frag_u { int i[4]; bf16x8 v; };

// Pack W -> Wp[kc=32][n=192][32k] bf16 (B-frag lane-linear). Wq pre-scaled 1/32.
__global__ void prep_w(const float* __restrict__ Wq, const float* __restrict__ Wk,
                       const float* __restrict__ Wv, unsigned short* __restrict__ Wp) {
    int id = blockIdx.x * 256 + threadIdx.x;        // 0..196607
    int wsel = id >> 16;
    int t = id & 65535;                             // = k*64 + n0 (coalesced read)
    int k = t >> 6, n0 = t & 63;
    const float* W = (wsel == 0) ? Wq : (wsel == 1) ? Wk : Wv;
    float v = W[t];
    if (wsel == 0) v *= 0.03125f;                   // 1/sqrt(1024)
    int n = wsel * 64 + n0;
    Wp[(k >> 5) * 6144 + n * 32 + (k & 31)] = f2bf(v);
}

// Projection: 512 blocks x 32 rows. Each wave = one K-quarter, processing TWO
// 16-row A-frags per W load (halves W L2 traffic); explicit X prefetch of
// iter+1 keeps loads in flight. Two-phase LDS reduction, wave 0 writes the
// attention-fragment-packed epilogue.
__global__ __launch_bounds__(256, 3) void proj_kernel(const float* __restrict__ X,
        const unsigned short* __restrict__ Wp, unsigned short* __restrict__ Qp,
        unsigned short* __restrict__ Kp, unsigned short* __restrict__ Vp) {
    __shared__ float cmb[3][64][52];
    const int lane = threadIdx.x & 63, wave = threadIdx.x >> 6;
    const int col = lane & 15, quad = lane >> 4;
    const int row0 = blockIdx.x * 32;
    const int fragoff = col * 64 + quad * 16;       // bytes, packed-frag loads
    const int perm = (col * 4 + quad) * 4;          // bpermute byte index

    f32x4 acc[2][12];
#pragma unroll
    for (int m = 0; m < 2; m++)
#pragma unroll
        for (int t = 0; t < 12; t++) acc[m][t] = (f32x4)(0.0f);

    const float* xb0 = X + (size_t)(row0 + (lane >> 2)) * EMB + wave * 256 + (lane & 3) * 8;
    const float* xb1 = xb0 + 16 * EMB;
    const char* wB = (const char*)Wp + (size_t)wave * 8 * 12288 + fragoff;

    float4 xa0 = *(const float4*)(xb0);
    float4 xc0 = *(const float4*)(xb0 + 4);
    float4 xa1 = *(const float4*)(xb1);
    float4 xc1 = *(const float4*)(xb1 + 4);

    for (int kc = 0; kc < 8; kc++) {
        float4 na0, nc0, na1, nc1;
        if (kc < 7) {
            const float* n0 = xb0 + (kc + 1) * 32;
            const float* n1 = xb1 + (kc + 1) * 32;
            na0 = *(const float4*)(n0);
            nc0 = *(const float4*)(n0 + 4);
            na1 = *(const float4*)(n1);
            nc1 = *(const float4*)(n1 + 4);
        }
        frag_u A0, A1;
        A0.i[0] = __builtin_amdgcn_ds_bpermute(perm, pk2bf(xa0.x, xa0.y));
        A0.i[1] = __builtin_amdgcn_ds_bpermute(perm, pk2bf(xa0.z, xa0.w));
        A0.i[2] = __builtin_amdgcn_ds_bpermute(perm, pk2bf(xc0.x, xc0.y));
        A0.i[3] = __builtin_amdgcn_ds_bpermute(perm, pk2bf(xc0.z, xc0.w));
        A1.i[0] = __builtin_amdgcn_ds_bpermute(perm, pk2bf(xa1.x, xa1.y));
        A1.i[1] = __builtin_amdgcn_ds_bpermute(perm, pk2bf(xa1.z, xa1.w));
        A1.i[2] = __builtin_amdgcn_ds_bpermute(perm, pk2bf(xc1.x, xc1.y));
        A1.i[3] = __builtin_amdgcn_ds_bpermute(perm, pk2bf(xc1.z, xc1.w));
        const char* wp = wB + kc * 12288;
#pragma unroll
        for (int t = 0; t < 12; t++) {
            const bf16x8 w = *(const bf16x8*)(wp + t * 1024);
            acc[0][t] = MFMA16(A0.v, w, acc[0][t], 0, 0, 0);
            acc[1][t] = MFMA16(A1.v, w, acc[1][t], 0, 0, 0);
        }
        xa0 = na0; xc0 = nc0; xa1 = na1; xc1 = nc1;
    }

    // two-phase reduction across K-quarter waves (40 KB LDS)
#pragma unroll
    for (int m = 0; m < 2; m++) {
        if (wave) {
#pragma unroll
            for (int t = 0; t < 12; t++)
                *(f32x4*)&cmb[wave - 1][lane][t * 4] = acc[m][t];
        }
        __syncthreads();
        if (wave == 0) {
#pragma unroll
            for (int s = 0; s < 3; s++)
#pragma unroll
                for (int t = 0; t < 12; t++)
                    acc[m][t] += *(const f32x4*)&cmb[s][lane][t * 4];
        }
        __syncthreads();
    }

    if (wave == 0) {
#pragma unroll
        for (int m = 0; m < 2; m++) {
            const int row0m = row0 + m * 16;
            const int tile = row0m >> 4;
            const int c = row0m >> 5;
            const int j = (row0m >> 4) & 1;
            // Q: packed A-frag layout
#pragma unroll
            for (int t = 0; t < 4; t++)
#pragma unroll
                for (int r = 0; r < 4; r++)
                    Qp[tile * 1024 + (t >> 1) * 512 + (quad * 4 + r) * 32 +
                       ((t & 1) * 2 + (col >> 3)) * 8 + (col & 7)] = f2bf(acc[m][t][r]);
            // K
#pragma unroll
            for (int tt = 0; tt < 4; tt++)
#pragma unroll
                for (int r = 0; r < 4; r++)
                    Kp[((c * 2 + j) * 2 + (tt >> 1)) * 512 + (quad * 4 + r) * 32 +
                       ((tt & 1) * 2 + (col >> 3)) * 8 + (col & 7)] = f2bf(acc[m][tt + 4][r]);
            // V: Vp[c][d][tok%32]
#pragma unroll
            for (int t4 = 0; t4 < 4; t4++) {
                ushort4 pk;
                pk.x = f2bf(acc[m][t4 + 8][0]); pk.y = f2bf(acc[m][t4 + 8][1]);
                pk.z = f2bf(acc[m][t4 + 8][2]); pk.w = f2bf(acc[m][t4 + 8][3]);
                *(ushort4*)&Vp[c * 2048 + t4 * 512 + col * 32 + j * 16 + quad * 4] = pk;
            }
        }
    }
}

// Flash attention: 512 blocks x 512 threads (8 waves), block = (batch, 32-row
// q-tile) heavy-first. Chunks split 8 ways (fixed m=0 partials additive);
// next-chunk K/V register prefetch; staged LDS tree reduction at the end.
__global__ __launch_bounds__(512, 4) void attn_kernel(const unsigned short* __restrict__ Qp,
        const unsigned short* __restrict__ Kp, const unsigned short* __restrict__ Vp,
        float* __restrict__ Out) {
    __shared__ float cmb[4][2][64][20];            // 40 KB
    __shared__ unsigned short plds[8][2][640];     // 20 KB
    const int lane = threadIdx.x & 63, wave = threadIdx.x >> 6;
    const int col = lane & 15, quad = lane >> 4;
    const int batch = blockIdx.x & 3;
    const int ti = 127 - (blockIdx.x >> 2);
    const int q0 = ti * 32;
    const size_t bT = (size_t)batch * TSEQ;
    const int fragoff = col * 64 + quad * 16;

    const char* QpB = (const char*)Qp;
    const char* KpB = (const char*)Kp;
    const char* VpB = (const char*)Vp;
    const int gt = (int)((bT + q0) >> 4);
    const int c0 = (int)(bT >> 5);

    bf16x8 aq[2][2];
#pragma unroll
    for (int m = 0; m < 2; m++)
#pragma unroll
        for (int h = 0; h < 2; h++)
            aq[m][h] = *(const bf16x8*)(QpB + (size_t)((gt + m) * 2 + h) * 1024 + fragoff);

    f32x4 o[2][4];
    f32x4 lsum[2];
#pragma unroll
    for (int m = 0; m < 2; m++) {
        lsum[m] = (f32x4)(0.0f);
#pragma unroll
        for (int t = 0; t < 4; t++) o[m][t] = (f32x4)(0.0f);
    }

    // preload first chunk (address valid even when wave > ti; result unused)
    bf16x8 bk[2][2], bv[4];
    {
        const char* kb = KpB + (size_t)(c0 + wave) * 4096;
        const char* vb = VpB + (size_t)(c0 + wave) * 4096;
#pragma unroll
        for (int j = 0; j < 2; j++)
#pragma unroll
            for (int h = 0; h < 2; h++)
                bk[j][h] = *(const bf16x8*)(kb + j * 2048 + h * 1024 + fragoff);
#pragma unroll
        for (int t = 0; t < 4; t++)
            bv[t] = *(const bf16x8*)(vb + t * 1024 + fragoff);
    }

    for (int c = wave; c <= ti; c += 8) {
        const bool more = (c + 8 <= ti);
        bf16x8 bkn[2][2], bvn[4];
        if (more) {
            const char* kb = KpB + (size_t)(c0 + c + 8) * 4096;
            const char* vb = VpB + (size_t)(c0 + c + 8) * 4096;
#pragma unroll
            for (int j = 0; j < 2; j++)
#pragma unroll
                for (int h = 0; h < 2; h++)
                    bkn[j][h] = *(const bf16x8*)(kb + j * 2048 + h * 1024 + fragoff);
#pragma unroll
            for (int t = 0; t < 4; t++)
                bvn[t] = *(const bf16x8*)(vb + t * 1024 + fragoff);
        }

        f32x4 s[2][2];
#pragma unroll
        for (int m = 0; m < 2; m++)
#pragma unroll
            for (int j = 0; j < 2; j++) {
                f32x4 a = MFMA16(aq[m][0], bk[j][0], (f32x4)(0.0f), 0, 0, 0);
                s[m][j] = MFMA16(aq[m][1], bk[j][1], a, 0, 0, 0);
            }
        const bool diag = (c == ti);
#pragma unroll
        for (int m = 0; m < 2; m++)
#pragma unroll
            for (int j = 0; j < 2; j++)
#pragma unroll
                for (int r = 0; r < 4; r++) {
                    float v = s[m][j][r];
                    if (diag && (j * 16 + col > m * 16 + quad * 4 + r)) v = -INFINITY;
                    const float p = __expf(v);   // |score| small: safe without max-sub
                    lsum[m][r] += p;
                    plds[wave][m][(quad * 4 + r) * 40 + j * 16 + col] =
                        (unsigned short)(__builtin_bit_cast(unsigned, p) >> 16);
                }
        bf16x8 pa[2];
#pragma unroll
        for (int m = 0; m < 2; m++)
            pa[m] = *(const bf16x8*)(&plds[wave][m][col * 40 + quad * 8]);
#pragma unroll
        for (int m = 0; m < 2; m++)
#pragma unroll
            for (int t = 0; t < 4; t++)
                o[m][t] = MFMA16(pa[m], bv[t], o[m][t], 0, 0, 0);

        if (more) {
#pragma unroll
            for (int j = 0; j < 2; j++)
#pragma unroll
                for (int h = 0; h < 2; h++)
                    bk[j][h] = bkn[j][h];
#pragma unroll
            for (int t = 0; t < 4; t++)
                bv[t] = bvn[t];
        }
    }

    // staged tree reduction: 8 -> 4 -> 2 -> 1 partials
    auto wr = [&](int s) {
#pragma unroll
        for (int m = 0; m < 2; m++) {
#pragma unroll
            for (int t = 0; t < 4; t++)
                *(f32x4*)&cmb[s][m][lane][t * 4] = o[m][t];
            *(f32x4*)&cmb[s][m][lane][16] = lsum[m];
        }
    };
    auto rd = [&](int s) {
#pragma unroll
        for (int m = 0; m < 2; m++) {
#pragma unroll
            for (int t = 0; t < 4; t++)
                o[m][t] += *(const f32x4*)&cmb[s][m][lane][t * 4];
            lsum[m] += *(const f32x4*)&cmb[s][m][lane][16];
        }
    };
    if (wave >= 4) wr(wave - 4);
    __syncthreads();
    if (wave < 4) rd(wave);
    __syncthreads();
    if (wave == 2 || wave == 3) wr(wave);
    __syncthreads();
    if (wave < 2) rd(wave + 2);
    __syncthreads();
    if (wave == 1) wr(1);
    __syncthreads();
    if (wave == 0) {
        rd(1);
#pragma unroll
        for (int off = 1; off < 16; off <<= 1)
#pragma unroll
            for (int m = 0; m < 2; m++)
#pragma unroll
                for (int r = 0; r < 4; r++)
                    lsum[m][r] += __shfl_xor(lsum[m][r], off, 64);
#pragma unroll
        for (int m = 0; m < 2; m++)
#pragma unroll
            for (int r = 0; r < 4; r++) {
                const float inv = 1.0f / lsum[m][r];
                const size_t orow = (bT + q0 + m * 16 + quad * 4 + r) * HD;
#pragma unroll
                for (int t = 0; t < 4; t++)
                    Out[orow + t * 16 + col] = o[m][t][r] * inv;
            }
    }
}

extern "C" void kernel_launch(void* const* d_in, const int* in_sizes, int n_in,
                              void* d_out, int out_size, void* d_ws, size_t ws_size,
                              hipStream_t stream) {
    const float* x  = (const float*)d_in[0];
    const float* Wq = (const float*)d_in[1];
    const float* Wk = (const float*)d_in[2];
    const float* Wv = (const float*)d_in[3];
    float* out = (float*)d_out;

    char* w = (char*)d_ws;
    unsigned short* Wp = (unsigned short*)(w);                            // 384 KB
    unsigned short* Qp = (unsigned short*)(w + (512 << 10));              // 2 MB
    unsigned short* Kp = (unsigned short*)(w + (512 << 10) + (2 << 20));  // 2 MB
    unsigned short* Vp = (unsigned short*)(w + (512 << 10) + (4 << 20));  // 2 MB

    hipLaunchKernelGGL(prep_w, dim3(768), dim3(256), 0, stream, Wq, Wk, Wv, Wp);
    hipLaunchKernelGGL(proj_kernel, dim3(512), dim3(256), 0, stream, x, Wp, Qp, Kp, Vp);
    hipLaunchKernelGGL(attn_kernel, dim3(512), dim3(512), 0, stream, Qp, Kp, Vp, out);
}

// Round 6
// 162.595 us; speedup vs baseline: 1.0572x; 1.0572x over previous
//
#include <hip/hip_runtime.h>
#include <hip/hip_bf16.h>
#include <math.h>

typedef __attribute__((ext_vector_type(8))) short bf16x8;
typedef __attribute__((ext_vector_type(4))) float f32x4;

#define MFMA16 __builtin_amdgcn_mfma_f32_16x16x32_bf16

static constexpr int TSEQ = 4096;
static constexpr int EMB = 1024;
static constexpr int HD = 64;

__device__ __forceinline__ unsigned short f2bf(float f) {
    unsigned u = __builtin_bit_cast(unsigned, f);
    u += 0x7fffu + ((u >> 16) & 1u);
    return (unsigned short)(u >> 16);
}
__device__ __forceinline__ int pk2bf(float a, float b) {
    return (int)((unsigned)f2bf(a) | ((unsigned)f2bf(b) << 16));
}

union frag_u { int i[4]; bf16x8 v; };

// Pack W -> Wp[kc=32][n=192][32k] bf16 (B-frag lane-linear). Wq pre-scaled 1/32.
__global__ void prep_w(const float* __restrict__ Wq, const float* __restrict__ Wk,
                       const float* __restrict__ Wv, unsigned short* __restrict__ Wp) {
    int id = blockIdx.x * 256 + threadIdx.x;        // 0..196607
    int wsel = id >> 16;
    int t = id & 65535;                             // = k*64 + n0 (coalesced read)
    int k = t >> 6, n0 = t & 63;
    const float* W = (wsel == 0) ? Wq : (wsel == 1) ? Wk : Wv;
    float v = W[t];
    if (wsel == 0) v *= 0.03125f;                   // 1/sqrt(1024)
    int n = wsel * 64 + n0;
    Wp[(k >> 5) * 6144 + n * 32 + (k & 31)] = f2bf(v);
}

// Projection v3: 512 blocks x 256 thr, block = 32 rows x 192 cols, NO K-split
// (no reduction). Waves = (rowfrag rf) x (colhalf ch); each wave: 1 A-frag x
// 6 col-frags = 12 MFMAs per BK=64 step. X double-buffered through LDS,
// converted to bf16 at staging; piece-swizzle u^(row&7) makes A-frag
// ds_read_b128 conflict-free. Epilogue: wave-private packed Q/K/V writes.
__global__ __launch_bounds__(256, 2) void proj_kernel(const float* __restrict__ X,
        const unsigned short* __restrict__ Wp, unsigned short* __restrict__ Qp,
        unsigned short* __restrict__ Kp, unsigned short* __restrict__ Vp) {
    __shared__ unsigned short xt[2][32][64];        // [buf][row][k], 8 KB, swizzled
    const int tid = threadIdx.x;
    const int lane = tid & 63, wave = tid >> 6;
    const int col = lane & 15, quad = lane >> 4;
    const int rf = wave & 1, ch = wave >> 1;
    const int row0 = blockIdx.x * 32;

    // staging: thread t -> (row = t>>3, piece = t&7), piece = 8 consecutive floats
    const int srow = tid >> 3;
    const int spiece = tid & 7;
    const float* gx = X + (size_t)(row0 + srow) * EMB + spiece * 8;
    const int sdst = ((spiece ^ (srow & 7)) * 8);   // swizzled piece offset (ushorts)

    // compute: A-frag row and swizzled piece indices for k-halves h=0,1
    const int arow = rf * 16 + col;
    const int apu0 = (0 * 4 + quad) ^ (arow & 7);
    const int apu1 = (1 * 4 + quad) ^ (arow & 7);

    const int fragoff = col * 64 + quad * 16;       // bytes within a 1KB W frag
    const char* wB = (const char*)Wp + ch * 6 * 1024 + fragoff;

    f32x4 acc[6];
#pragma unroll
    for (int t = 0; t < 6; t++) acc[t] = (f32x4)(0.0f);

    // prologue: stage kc=0 into buf 0
    {
        const float4 xa = *(const float4*)(gx);
        const float4 xb = *(const float4*)(gx + 4);
        frag_u u;
        u.i[0] = pk2bf(xa.x, xa.y); u.i[1] = pk2bf(xa.z, xa.w);
        u.i[2] = pk2bf(xb.x, xb.y); u.i[3] = pk2bf(xb.z, xb.w);
        *(bf16x8*)&xt[0][srow][sdst] = u.v;
    }
    __syncthreads();

    int buf = 0;
    for (int kc = 0; kc < 16; kc++) {
        float4 xa, xb;
        if (kc < 15) {
            const float* g = gx + (kc + 1) * 64;
            xa = *(const float4*)(g);
            xb = *(const float4*)(g + 4);
        }
        const bf16x8 a0 = *(const bf16x8*)&xt[buf][arow][apu0 * 8];
        const bf16x8 a1 = *(const bf16x8*)&xt[buf][arow][apu1 * 8];
        const char* wp = wB + kc * 24576;           // kstep 2kc (then +12288 for 2kc+1)
#pragma unroll
        for (int cf = 0; cf < 6; cf++) {
            const bf16x8 w0 = *(const bf16x8*)(wp + cf * 1024);
            const bf16x8 w1 = *(const bf16x8*)(wp + 12288 + cf * 1024);
            acc[cf] = MFMA16(a0, w0, acc[cf], 0, 0, 0);
            acc[cf] = MFMA16(a1, w1, acc[cf], 0, 0, 0);
        }
        if (kc < 15) {
            frag_u u;
            u.i[0] = pk2bf(xa.x, xa.y); u.i[1] = pk2bf(xa.z, xa.w);
            u.i[2] = pk2bf(xb.x, xb.y); u.i[3] = pk2bf(xb.z, xb.w);
            *(bf16x8*)&xt[buf ^ 1][srow][sdst] = u.v;
        }
        __syncthreads();
        buf ^= 1;
    }

    // epilogue: wave-private. This wave owns rows rf*16..+16, cols ch*96..+96.
    const int tile = blockIdx.x * 2 + rf;           // 16-row group index
    const int c = blockIdx.x;                       // 32-row chunk index
    const int j = rf;
#pragma unroll
    for (int cf = 0; cf < 6; cf++) {
        const int n0 = ch * 96 + cf * 16;           // compile-time per (ch,cf) after unroll
        if (n0 < 64) {
            const int t = n0 >> 4;
#pragma unroll
            for (int r = 0; r < 4; r++)
                Qp[tile * 1024 + (t >> 1) * 512 + (quad * 4 + r) * 32 +
                   ((t & 1) * 2 + (col >> 3)) * 8 + (col & 7)] = f2bf(acc[cf][r]);
        } else if (n0 < 128) {
            const int tt = (n0 - 64) >> 4;
#pragma unroll
            for (int r = 0; r < 4; r++)
                Kp[((c * 2 + j) * 2 + (tt >> 1)) * 512 + (quad * 4 + r) * 32 +
                   ((tt & 1) * 2 + (col >> 3)) * 8 + (col & 7)] = f2bf(acc[cf][r]);
        } else {
            const int t4 = (n0 - 128) >> 4;
            ushort4 pk;
            pk.x = f2bf(acc[cf][0]); pk.y = f2bf(acc[cf][1]);
            pk.z = f2bf(acc[cf][2]); pk.w = f2bf(acc[cf][3]);
            *(ushort4*)&Vp[c * 2048 + t4 * 512 + col * 32 + j * 16 + quad * 4] = pk;
        }
    }
}

// Flash attention (R4 version): 512 blocks x 512 threads (8 waves), block =
// (batch, 32-row q-tile) heavy-first. Chunks split 8 ways (fixed m=0 partials
// additive); staged LDS tree reduction at the end. No prefetch (spills @128 cap).
__global__ __launch_bounds__(512, 4) void attn_kernel(const unsigned short* __restrict__ Qp,
        const unsigned short* __restrict__ Kp, const unsigned short* __restrict__ Vp,
        float* __restrict__ Out) {
    __shared__ float cmb[4][2][64][20];            // 40 KB
    __shared__ unsigned short plds[8][2][640];     // 20 KB
    const int lane = threadIdx.x & 63, wave = threadIdx.x >> 6;
    const int col = lane & 15, quad = lane >> 4;
    const int batch = blockIdx.x & 3;
    const int ti = 127 - (blockIdx.x >> 2);
    const int q0 = ti * 32;
    const size_t bT = (size_t)batch * TSEQ;
    const int fragoff = col * 64 + quad * 16;

    const char* QpB = (const char*)Qp;
    const char* KpB = (const char*)Kp;
    const char* VpB = (const char*)Vp;
    const int gt = (int)((bT + q0) >> 4);
    const int c0 = (int)(bT >> 5);

    bf16x8 aq[2][2];
#pragma unroll
    for (int m = 0; m < 2; m++)
#pragma unroll
        for (int h = 0; h < 2; h++)
            aq[m][h] = *(const bf16x8*)(QpB + (size_t)((gt + m) * 2 + h) * 1024 + fragoff);

    f32x4 o[2][4];
    f32x4 lsum[2];
#pragma unroll
    for (int m = 0; m < 2; m++) {
        lsum[m] = (f32x4)(0.0f);
#pragma unroll
        for (int t = 0; t < 4; t++) o[m][t] = (f32x4)(0.0f);
    }

    for (int c = wave; c <= ti; c += 8) {
        const char* kb = KpB + (size_t)(c0 + c) * 4096;
        const char* vb = VpB + (size_t)(c0 + c) * 4096;
        bf16x8 bk[2][2], bv[4];
#pragma unroll
        for (int j = 0; j < 2; j++)
#pragma unroll
            for (int h = 0; h < 2; h++)
                bk[j][h] = *(const bf16x8*)(kb + j * 2048 + h * 1024 + fragoff);
#pragma unroll
        for (int t = 0; t < 4; t++)
            bv[t] = *(const bf16x8*)(vb + t * 1024 + fragoff);

        f32x4 s[2][2];
#pragma unroll
        for (int m = 0; m < 2; m++)
#pragma unroll
            for (int j = 0; j < 2; j++) {
                f32x4 a = MFMA16(aq[m][0], bk[j][0], (f32x4)(0.0f), 0, 0, 0);
                s[m][j] = MFMA16(aq[m][1], bk[j][1], a, 0, 0, 0);
            }
        const bool diag = (c == ti);
#pragma unroll
        for (int m = 0; m < 2; m++)
#pragma unroll
            for (int j = 0; j < 2; j++)
#pragma unroll
                for (int r = 0; r < 4; r++) {
                    float v = s[m][j][r];
                    if (diag && (j * 16 + col > m * 16 + quad * 4 + r)) v = -INFINITY;
                    const float p = __expf(v);   // |score| small: safe without max-sub
                    lsum[m][r] += p;
                    plds[wave][m][(quad * 4 + r) * 40 + j * 16 + col] =
                        (unsigned short)(__builtin_bit_cast(unsigned, p) >> 16);
                }
        bf16x8 pa[2];
#pragma unroll
        for (int m = 0; m < 2; m++)
            pa[m] = *(const bf16x8*)(&plds[wave][m][col * 40 + quad * 8]);
#pragma unroll
        for (int m = 0; m < 2; m++)
#pragma unroll
            for (int t = 0; t < 4; t++)
                o[m][t] = MFMA16(pa[m], bv[t], o[m][t], 0, 0, 0);
    }

    // staged tree reduction: 8 -> 4 -> 2 -> 1 partials
    auto wr = [&](int s) {
#pragma unroll
        for (int m = 0; m < 2; m++) {
#pragma unroll
            for (int t = 0; t < 4; t++)
                *(f32x4*)&cmb[s][m][lane][t * 4] = o[m][t];
            *(f32x4*)&cmb[s][m][lane][16] = lsum[m];
        }
    };
    auto rd = [&](int s) {
#pragma unroll
        for (int m = 0; m < 2; m++) {
#pragma unroll
            for (int t = 0; t < 4; t++)
                o[m][t] += *(const f32x4*)&cmb[s][m][lane][t * 4];
            lsum[m] += *(const f32x4*)&cmb[s][m][lane][16];
        }
    };
    if (wave >= 4) wr(wave - 4);
    __syncthreads();
    if (wave < 4) rd(wave);
    __syncthreads();
    if (wave == 2 || wave == 3) wr(wave);
    __syncthreads();
    if (wave < 2) rd(wave + 2);
    __syncthreads();
    if (wave == 1) wr(1);
    __syncthreads();
    if (wave == 0) {
        rd(1);
#pragma unroll
        for (int off = 1; off < 16; off <<= 1)
#pragma unroll
            for (int m = 0; m < 2; m++)
#pragma unroll
                for (int r = 0; r < 4; r++)
                    lsum[m][r] += __shfl_xor(lsum[m][r], off, 64);
#pragma unroll
        for (int m = 0; m < 2; m++)
#pragma unroll
            for (int r = 0; r < 4; r++) {
                const float inv = 1.0f / lsum[m][r];
                const size_t orow = (bT + q0 + m * 16 + quad * 4 + r) * HD;
#pragma unroll
                for (int t = 0; t < 4; t++)
                    Out[orow + t * 16 + col] = o[m][t][r] * inv;
            }
    }
}

extern "C" void kernel_launch(void* const* d_in, const int* in_sizes, int n_in,
                              void* d_out, int out_size, void* d_ws, size_t ws_size,
                              hipStream_t stream) {
    const float* x  = (const float*)d_in[0];
    const float* Wq = (const float*)d_in[1];
    const float* Wk = (const float*)d_in[2];
    const float* Wv = (const float*)d_in[3];
    float* out = (float*)d_out;

    char* w = (char*)d_ws;
    unsigned short* Wp = (unsigned short*)(w);                            // 384 KB
    unsigned short* Qp = (unsigned short*)(w + (512 << 10));              // 2 MB
    unsigned short* Kp = (unsigned short*)(w + (512 << 10) + (2 << 20));  // 2 MB
    unsigned short* Vp = (unsigned short*)(w + (512 << 10) + (4 << 20));  // 2 MB

    hipLaunchKernelGGL(prep_w, dim3(768), dim3(256), 0, stream, Wq, Wk, Wv, Wp);
    hipLaunchKernelGGL(proj_kernel, dim3(512), dim3(256), 0, stream, x, Wp, Qp, Kp, Vp);
    hipLaunchKernelGGL(attn_kernel, dim3(512), dim3(512), 0, stream, Qp, Kp, Vp, out);
}